// Round 5
// baseline (2844.324 us; speedup 1.0000x reference)
//
#include <hip/hip_runtime.h>

// GCN-VAE forward, fp32 pipeline, dtype-adaptive inputs, fp32 outputs.
// flag[0] = bf16-view NaN patterns in x   (>64  -> float inputs are fp32)
// flag[1] = zero hi-words in edge pairs   (>E/2 -> edge_index is int64)
// flag[2] = overflow-edge count (ELL slots exceeded; handled by k_spill)
// R3: ELL (64 slots) XCD-sliced build killed k_fill's 15x write amplification.
// R4: k_mlp was scalar-load-latency-bound (VALUBusy 18.5%) -> weights repacked
//     with x4-padded rows, staged in LDS, float4 broadcast reads, 2 nodes/thread.

#define NEG 0.01f
#define GS 64        // g row stride (floats) -> 256B rows
#define ELLS 64      // ELL slots per node
#define SLICES 16    // 2 passes x 8 xcd groups
#define SPILL_CAP 65536

// padded weight-block offsets (floats; every offset & row stride multiple of 4)
#define O_WE1 0      // 40 x 52
#define O_BE1 2080   // 40
#define O_WE2 2120   // 30 x 40
#define O_BE2 3320   // 32
#define O_WE3 3352   // 20 x 32
#define O_BE3 3992   // 20
#define O_WFC 4012   // 10 x 12
#define O_BFC 4132   // 12
#define O_WD1 4144   // 20 x 12
#define O_BD1 4384   // 20
#define O_WD2 4404   // 40 x 20
#define O_BD2 5204   // 40
#define O_WD3 5244   // 50 x 40
#define O_BD3 7244   // 52
#define MLP_LDS 7296 // floats staged into LDS by k_mlp (29184 B)
#define O_WG 7296    // 50 x 52 (k_g only)
#define O_BG 9896    // 52 (k_gather only)
#define W_TOT 9952

static __device__ __forceinline__ float bf2f(unsigned short u) {
    return __uint_as_float(((unsigned)u) << 16);
}
static __device__ __forceinline__ float leaky(float a) { return (a >= 0.f) ? a : NEG * a; }

__global__ void k_zero(int* __restrict__ indeg, int* __restrict__ flag, int n) {
    int i = blockIdx.x * 256 + threadIdx.x;
    if (i < n) indeg[i] = 0;
    if (i == 0) { flag[0] = 0; flag[1] = 0; flag[2] = 0; }
}

// blocks [0,2048): scan N*75 words of x for bf16-view NaN/Inf exponent patterns.
// blocks [2048,4096): scan E word-pairs of edge_index for zero hi-words.
__global__ void k_detect(const unsigned* __restrict__ x, long xwords,
                         const unsigned* __restrict__ ei, long epairs,
                         int* __restrict__ flag) {
    const long stride = 2048L * 256;
    if (blockIdx.x < 2048) {
        long i = (long)blockIdx.x * 256 + threadIdx.x;
        int c = 0;
        for (; i < xwords; i += stride) {
            unsigned w = x[i];
            if (((w >> 23) & 0xFFu) == 0xFFu || ((w >> 7) & 0xFFu) == 0xFFu) c++;
        }
        if (c) atomicAdd(&flag[0], c);
    } else {
        long i = (long)(blockIdx.x - 2048) * 256 + threadIdx.x;
        int c = 0;
        for (; i < epairs; i += stride)
            if (ei[2 * i + 1] == 0u) c++;
        if (c) atomicAdd(&flag[1], c);
    }
}

// ELL build, XCD-sliced: 8192 blocks = 2 passes x (8 xcd-groups x 512).
__global__ void k_build(const int* __restrict__ ei, int* __restrict__ indeg,
                        int* __restrict__ ebuf, int2* __restrict__ spill,
                        int* __restrict__ flag, int E, int N) {
    int blk = blockIdx.x;
    int pass = blk >> 12;
    int x = blk & 7;
    int q = (blk & 4095) >> 3;
    int s = pass * 8 + x;
    int sw = (N + SLICES - 1) / SLICES;
    int nlo = s * sw;
    int nhi = nlo + sw; if (nhi > N) nhi = N;
    bool is64 = flag[1] > (E >> 1);
    for (long e = (long)q * 256 + threadIdx.x; e < E; e += 512L * 256) {
        int d = is64 ? ei[2 * (E + e)] : ei[E + e];
        if (d < nlo || d >= nhi) continue;
        int src = is64 ? ei[2 * e] : ei[e];
        if ((unsigned)src >= (unsigned)N) continue;
        int c = atomicAdd(&indeg[d], 1);
        if (c < ELLS) {
            ebuf[(size_t)d * ELLS + c] = src;
        } else {
            int o = atomicAdd(&flag[2], 1);
            if (o < SPILL_CAP) spill[o] = make_int2(src, d);
        }
    }
}

__global__ void k_dinv(const int* __restrict__ indeg, float* __restrict__ dinv, int n) {
    int i = blockIdx.x * 256 + threadIdx.x;
    if (i < n) dinv[i] = rsqrtf(1.0f + (float)indeg[i]);  // deg includes self loop
}

// convert the 16 weight/bias arrays into the padded fp32 block (pads zeroed).
struct CW {
    const void* src[16];
    int off[16], rows[16], id[16], pd[16];
};
__global__ void k_convw(CW cw, float* __restrict__ dst, const int* __restrict__ flag) {
    int b = blockIdx.x;
    bool isf = flag[0] > 64;
    const float* sf = (const float*)cw.src[b];
    const unsigned short* sh = (const unsigned short*)cw.src[b];
    float* d = dst + cw.off[b];
    int id = cw.id[b], pd = cw.pd[b];
    int tot = cw.rows[b] * pd;
    for (int i = threadIdx.x; i < tot; i += 256) {
        int r = i / pd, c = i - r * pd;
        float v = 0.f;
        if (c < id) v = isf ? sf[r * id + c] : bf2f(sh[r * id + c]);
        d[i] = v;
    }
}

// g[i] = (x[i,100:150] @ Wg.T) * dinv[i] -> fp32 stride GS. Wg staged in LDS.
__global__ __launch_bounds__(256) void k_g(const void* __restrict__ xv,
                                           const float* __restrict__ W,
                                           const float* __restrict__ dinv,
                                           const int* __restrict__ flag,
                                           float* __restrict__ g, int n) {
    __shared__ float lwg[2600];  // 50 x 52
    {
        const float4* s4 = (const float4*)(W + O_WG);
        float4* d4 = (float4*)lwg;
        for (int k = threadIdx.x; k < 650; k += 256) d4[k] = s4[k];
    }
    __syncthreads();
    int i = blockIdx.x * 256 + threadIdx.x;
    if (i >= n) return;
    bool isf = flag[0] > 64;
    float xr[52];
    if (isf) {
        const float* p = (const float*)xv + (size_t)i * 150 + 100;
#pragma unroll
        for (int k = 0; k < 50; k++) xr[k] = p[k];
    } else {
        const unsigned short* p = (const unsigned short*)xv + (size_t)i * 150 + 100;
#pragma unroll
        for (int k = 0; k < 50; k++) xr[k] = bf2f(p[k]);
    }
    xr[50] = 0.f; xr[51] = 0.f;
    const float4* w4 = (const float4*)lwg;
    float di = dinv[i];
    float* gr = g + (size_t)i * GS;
#pragma unroll
    for (int f = 0; f < 50; f++) {
        float a = 0.f;
#pragma unroll
        for (int p = 0; p < 13; p++) {
            float4 w = w4[f * 13 + p];
            a += w.x * xr[4 * p] + w.y * xr[4 * p + 1] + w.z * xr[4 * p + 2] + w.w * xr[4 * p + 3];
        }
        gr[f] = a * di;
    }
}

// wave per node: lane f accumulates feature f over ELL edges; 8-way ILP.
__global__ __launch_bounds__(256) void k_gather(const float* __restrict__ g,
                                                const int* __restrict__ indeg,
                                                const int* __restrict__ ebuf,
                                                const float* __restrict__ dinv,
                                                const float* __restrict__ W,
                                                float* __restrict__ h1, int n) {
    int wid = threadIdx.x >> 6;
    int lane = threadIdx.x & 63;
    int i = blockIdx.x * 4 + wid;
    if (i >= n) return;
    int fc = lane < 50 ? lane : 49;
    int cnt = indeg[i];
    if (cnt > ELLS) cnt = ELLS;
    float di = dinv[i];
    int ev = (lane < cnt) ? ebuf[(size_t)i * ELLS + lane] : 0;
    float a0 = g[(size_t)i * GS + fc];  // self-loop (g pre-scaled by dinv[src])
    float a1 = 0.f, a2 = 0.f, a3 = 0.f, a4 = 0.f, a5 = 0.f, a6 = 0.f, a7 = 0.f;
    int m = 0;
    for (; m + 7 < cnt; m += 8) {
        int j0 = __shfl(ev, m);
        int j1 = __shfl(ev, m + 1);
        int j2 = __shfl(ev, m + 2);
        int j3 = __shfl(ev, m + 3);
        int j4 = __shfl(ev, m + 4);
        int j5 = __shfl(ev, m + 5);
        int j6 = __shfl(ev, m + 6);
        int j7 = __shfl(ev, m + 7);
        a0 += g[(size_t)j0 * GS + fc];
        a1 += g[(size_t)j1 * GS + fc];
        a2 += g[(size_t)j2 * GS + fc];
        a3 += g[(size_t)j3 * GS + fc];
        a4 += g[(size_t)j4 * GS + fc];
        a5 += g[(size_t)j5 * GS + fc];
        a6 += g[(size_t)j6 * GS + fc];
        a7 += g[(size_t)j7 * GS + fc];
    }
    for (; m < cnt; m++) {
        int j = __shfl(ev, m);
        a0 += g[(size_t)j * GS + fc];
    }
    if (lane < 50) {
        float h = (((a0 + a1) + (a2 + a3)) + ((a4 + a5) + (a6 + a7))) * di + W[O_BG + lane];
        h1[(size_t)i * 50 + lane] = h;
    }
}

// overflow edges (deg > ELLS): atomic-add their contribution into h1.
__global__ void k_spill(const int2* __restrict__ spill, const int* __restrict__ flag,
                        const float* __restrict__ g, const float* __restrict__ dinv,
                        float* __restrict__ h1) {
    int nov = flag[2];
    if (nov > SPILL_CAP) nov = SPILL_CAP;
    int lane = threadIdx.x & 63;
    int wave = (blockIdx.x * 256 + threadIdx.x) >> 6;
    for (int e = wave; e < nov; e += gridDim.x * 4) {
        int2 sd = spill[e];
        if (lane < 50)
            atomicAdd(&h1[(size_t)sd.y * 50 + lane], g[(size_t)sd.x * GS + lane] * dinv[sd.y]);
    }
}

// MLP chain: weights in LDS (float4 broadcast reads), 2 nodes per thread.
__global__ __launch_bounds__(256, 2) void k_mlp(const float* __restrict__ h1,
                                                const void* __restrict__ epsv,
                                                const float* __restrict__ W,
                                                const int* __restrict__ flag,
                                                float* __restrict__ out, int n) {
    __shared__ float lw[MLP_LDS];
    {
        const float4* s4 = (const float4*)W;
        float4* d4 = (float4*)lw;
        for (int k = threadIdx.x; k < MLP_LDS / 4; k += 256) d4[k] = s4[k];
    }
    __syncthreads();
    const float4* lw4 = (const float4*)lw;
    int i0 = blockIdx.x * 512 + threadIdx.x;
    if (i0 >= n) return;
    int i1 = i0 + 256;
    int idx[2];
    idx[0] = i0;
    idx[1] = (i1 < n) ? i1 : i0;  // tail: duplicate work, same writes, benign
    bool isf = flag[0] > 64;

    float v0[2][52];
#pragma unroll
    for (int j = 0; j < 2; j++) {
        const float* hr = h1 + (size_t)idx[j] * 50;
#pragma unroll
        for (int p = 0; p < 50; p++) v0[j][p] = hr[p];
        v0[j][50] = 0.f; v0[j][51] = 0.f;
    }
    float v1[2][40];
#pragma unroll
    for (int f = 0; f < 40; f++) {
        float a0 = lw[O_BE1 + f], a1 = a0;
#pragma unroll
        for (int p = 0; p < 13; p++) {
            float4 w = lw4[(O_WE1 >> 2) + f * 13 + p];
            a0 += w.x * v0[0][4 * p] + w.y * v0[0][4 * p + 1] + w.z * v0[0][4 * p + 2] + w.w * v0[0][4 * p + 3];
            a1 += w.x * v0[1][4 * p] + w.y * v0[1][4 * p + 1] + w.z * v0[1][4 * p + 2] + w.w * v0[1][4 * p + 3];
        }
        v1[0][f] = leaky(a0);
        v1[1][f] = leaky(a1);
    }
    float v2[2][32];
#pragma unroll
    for (int f = 0; f < 30; f++) {
        float a0 = lw[O_BE2 + f], a1 = a0;
#pragma unroll
        for (int p = 0; p < 10; p++) {
            float4 w = lw4[(O_WE2 >> 2) + f * 10 + p];
            a0 += w.x * v1[0][4 * p] + w.y * v1[0][4 * p + 1] + w.z * v1[0][4 * p + 2] + w.w * v1[0][4 * p + 3];
            a1 += w.x * v1[1][4 * p] + w.y * v1[1][4 * p + 1] + w.z * v1[1][4 * p + 2] + w.w * v1[1][4 * p + 3];
        }
        v2[0][f] = leaky(a0);
        v2[1][f] = leaky(a1);
    }
    v2[0][30] = v2[0][31] = v2[1][30] = v2[1][31] = 0.f;

    float v3[2][20];  // [mu(10) | log_var(10)]
#pragma unroll
    for (int f = 0; f < 20; f++) {
        float a0 = lw[O_BE3 + f], a1 = a0;
#pragma unroll
        for (int p = 0; p < 8; p++) {
            float4 w = lw4[(O_WE3 >> 2) + f * 8 + p];
            a0 += w.x * v2[0][4 * p] + w.y * v2[0][4 * p + 1] + w.z * v2[0][4 * p + 2] + w.w * v2[0][4 * p + 3];
            a1 += w.x * v2[1][4 * p] + w.y * v2[1][4 * p + 1] + w.z * v2[1][4 * p + 2] + w.w * v2[1][4 * p + 3];
        }
        v3[0][f] = a0;
        v3[1][f] = a1;
    }
    float z1[2][12], z[2][12];
#pragma unroll
    for (int j = 0; j < 2; j++) {
        float ev[10];
        if (isf) {
            const float* p = (const float*)epsv + (size_t)idx[j] * 10;
#pragma unroll
            for (int k = 0; k < 10; k++) ev[k] = p[k];
        } else {
            const unsigned short* p = (const unsigned short*)epsv + (size_t)idx[j] * 10;
#pragma unroll
            for (int k = 0; k < 10; k++) ev[k] = bf2f(p[k]);
        }
#pragma unroll
        for (int k = 0; k < 10; k++) z1[j][k] = v3[j][k] + ev[k] * expf(0.5f * v3[j][10 + k]);
        z1[j][10] = z1[j][11] = 0.f;
    }
#pragma unroll
    for (int f = 0; f < 10; f++) {
        float a0 = lw[O_BFC + f], a1 = a0;
#pragma unroll
        for (int p = 0; p < 3; p++) {
            float4 w = lw4[(O_WFC >> 2) + f * 3 + p];
            a0 += w.x * z1[0][4 * p] + w.y * z1[0][4 * p + 1] + w.z * z1[0][4 * p + 2] + w.w * z1[0][4 * p + 3];
            a1 += w.x * z1[1][4 * p] + w.y * z1[1][4 * p + 1] + w.z * z1[1][4 * p + 2] + w.w * z1[1][4 * p + 3];
        }
        z[0][f] = (a0 > 0.f) ? a0 : 0.f;
        z[1][f] = (a1 > 0.f) ? a1 : 0.f;
    }
    z[0][10] = z[0][11] = z[1][10] = z[1][11] = 0.f;

    float d1[2][20];
#pragma unroll
    for (int f = 0; f < 20; f++) {
        float a0 = lw[O_BD1 + f], a1 = a0;
#pragma unroll
        for (int p = 0; p < 3; p++) {
            float4 w = lw4[(O_WD1 >> 2) + f * 3 + p];
            a0 += w.x * z[0][4 * p] + w.y * z[0][4 * p + 1] + w.z * z[0][4 * p + 2] + w.w * z[0][4 * p + 3];
            a1 += w.x * z[1][4 * p] + w.y * z[1][4 * p + 1] + w.z * z[1][4 * p + 2] + w.w * z[1][4 * p + 3];
        }
        d1[0][f] = leaky(a0);
        d1[1][f] = leaky(a1);
    }
    float d2[2][40];
#pragma unroll
    for (int f = 0; f < 40; f++) {
        float a0 = lw[O_BD2 + f], a1 = a0;
#pragma unroll
        for (int p = 0; p < 5; p++) {
            float4 w = lw4[(O_WD2 >> 2) + f * 5 + p];
            a0 += w.x * d1[0][4 * p] + w.y * d1[0][4 * p + 1] + w.z * d1[0][4 * p + 2] + w.w * d1[0][4 * p + 3];
            a1 += w.x * d1[1][4 * p] + w.y * d1[1][4 * p + 1] + w.z * d1[1][4 * p + 2] + w.w * d1[1][4 * p + 3];
        }
        d2[0][f] = leaky(a0);
        d2[1][f] = leaky(a1);
    }
    // outputs (fp32): mu'(N*50) | mu(N*10) | log_var(N*10) | z(N*10)
#pragma unroll
    for (int f = 0; f < 50; f++) {
        float a0 = lw[O_BD3 + f], a1 = a0;
#pragma unroll
        for (int p = 0; p < 10; p++) {
            float4 w = lw4[(O_WD3 >> 2) + f * 10 + p];
            a0 += w.x * d2[0][4 * p] + w.y * d2[0][4 * p + 1] + w.z * d2[0][4 * p + 2] + w.w * d2[0][4 * p + 3];
            a1 += w.x * d2[1][4 * p] + w.y * d2[1][4 * p + 1] + w.z * d2[1][4 * p + 2] + w.w * d2[1][4 * p + 3];
        }
        out[(size_t)idx[0] * 50 + f] = 1.f / (1.f + expf(-a0));
        out[(size_t)idx[1] * 50 + f] = 1.f / (1.f + expf(-a1));
    }
#pragma unroll
    for (int j = 0; j < 2; j++) {
        float* o_mu = out + (size_t)n * 50 + (size_t)idx[j] * 10;
        float* o_lv = out + (size_t)n * 60 + (size_t)idx[j] * 10;
        float* o_z = out + (size_t)n * 70 + (size_t)idx[j] * 10;
#pragma unroll
        for (int p = 0; p < 10; p++) {
            o_mu[p] = v3[j][p];
            o_lv[p] = v3[j][10 + p];
            o_z[p] = z[j][p];
        }
    }
}

extern "C" void kernel_launch(void* const* d_in, const int* in_sizes, int n_in,
                              void* d_out, int out_size, void* d_ws, size_t ws_size,
                              hipStream_t stream) {
    const int N = in_sizes[0] / 150;
    const int E = in_sizes[1] / 2;

    char* w = (char*)d_ws;
    auto alloc = [&](size_t bytes) {
        void* p = (void*)w;
        w += (bytes + 255) & ~(size_t)255;
        return p;
    };
    int* indeg = (int*)alloc((size_t)N * 4);
    int* flag = (int*)alloc(256);
    float* dinv = (float*)alloc((size_t)N * 4);
    float* Wall = (float*)alloc((size_t)W_TOT * 4);
    int2* spill = (int2*)alloc((size_t)SPILL_CAP * 8);
    float* g = (float*)alloc((size_t)N * GS * 4);
    float* h1 = (float*)alloc((size_t)N * 50 * 4);
    int* ebuf = (int*)alloc((size_t)N * ELLS * 4);

    CW cw;
    static const int co[16] = {O_WG, O_BG, O_WE1, O_BE1, O_WE2, O_BE2, O_WE3, O_BE3,
                               O_WFC, O_BFC, O_WD1, O_BD1, O_WD2, O_BD2, O_WD3, O_BD3};
    static const int cr[16] = {50, 1, 40, 1, 30, 1, 20, 1, 10, 1, 20, 1, 40, 1, 50, 1};
    static const int ci[16] = {50, 50, 50, 40, 40, 30, 30, 20, 10, 10, 10, 20, 20, 40, 40, 50};
    static const int cp[16] = {52, 52, 52, 40, 40, 32, 32, 20, 12, 12, 12, 20, 20, 40, 40, 52};
    for (int k = 0; k < 16; k++) {
        cw.src[k] = d_in[3 + k];
        cw.off[k] = co[k];
        cw.rows[k] = cr[k];
        cw.id[k] = ci[k];
        cw.pd[k] = cp[k];
    }

    int nbN = (N + 255) / 256;
    int nbM = (N + 511) / 512;

    k_zero<<<nbN, 256, 0, stream>>>(indeg, flag, N);
    k_detect<<<4096, 256, 0, stream>>>((const unsigned*)d_in[0], (long)N * 75,
                                       (const unsigned*)d_in[1], (long)E, flag);
    k_build<<<8192, 256, 0, stream>>>((const int*)d_in[1], indeg, ebuf, spill, flag, E, N);
    k_dinv<<<nbN, 256, 0, stream>>>(indeg, dinv, N);
    k_convw<<<16, 256, 0, stream>>>(cw, Wall, flag);
    k_g<<<nbN, 256, 0, stream>>>(d_in[0], Wall, dinv, flag, g, N);
    k_gather<<<(N + 3) / 4, 256, 0, stream>>>(g, indeg, ebuf, dinv, Wall, h1, N);
    k_spill<<<64, 256, 0, stream>>>(spill, flag, g, dinv, h1);
    k_mlp<<<nbM, 256, 0, stream>>>(h1, d_in[2], Wall, flag, (float*)d_out, N);
}

// Round 6
// 2727.306 us; speedup vs baseline: 1.0429x; 1.0429x over previous
//
#include <hip/hip_runtime.h>

// GCN-VAE forward, fp32 pipeline, dtype-adaptive inputs, fp32 outputs.
// flag[0] = bf16-view NaN patterns in x   (>64  -> float inputs are fp32)
// flag[1] = zero hi-words in edge pairs   (>E/2 -> edge_index is int64)
// flag[2] = overflow-edge count (ELL slots exceeded; handled by k_spill)
// R3: ELL (64 slots) XCD-sliced build killed k_fill's 15x write amplification.
// R4: k_mlp scalar-load-latency-bound -> weights to LDS (float4 broadcast).
// R5: 2 nodes/thread + vgpr cap 128 -> 5.26GB scratch spill. Lesson: 1 node
//     per thread, NO min-waves bound; let allocator take ~180 VGPRs.

#define NEG 0.01f
#define GS 64        // g row stride (floats) -> 256B rows
#define ELLS 64      // ELL slots per node
#define SLICES 16    // 2 passes x 8 xcd groups
#define SPILL_CAP 65536

// padded weight-block offsets (floats; every offset & row stride multiple of 4)
#define O_WE1 0      // 40 x 52
#define O_BE1 2080   // 40
#define O_WE2 2120   // 30 x 40
#define O_BE2 3320   // 32
#define O_WE3 3352   // 20 x 32
#define O_BE3 3992   // 20
#define O_WFC 4012   // 10 x 12
#define O_BFC 4132   // 12
#define O_WD1 4144   // 20 x 12
#define O_BD1 4384   // 20
#define O_WD2 4404   // 40 x 20
#define O_BD2 5204   // 40
#define O_WD3 5244   // 50 x 40
#define O_BD3 7244   // 52
#define MLP_LDS 7296 // floats staged into LDS by k_mlp (29184 B)
#define O_WG 7296    // 50 x 52 (k_g only)
#define O_BG 9896    // 52 (k_gather only)
#define W_TOT 9952

static __device__ __forceinline__ float bf2f(unsigned short u) {
    return __uint_as_float(((unsigned)u) << 16);
}
static __device__ __forceinline__ float leaky(float a) { return (a >= 0.f) ? a : NEG * a; }

__global__ void k_zero(int* __restrict__ indeg, int* __restrict__ flag, int n) {
    int i = blockIdx.x * 256 + threadIdx.x;
    if (i < n) indeg[i] = 0;
    if (i == 0) { flag[0] = 0; flag[1] = 0; flag[2] = 0; }
}

// blocks [0,2048): scan N*75 words of x for bf16-view NaN/Inf exponent patterns.
// blocks [2048,4096): scan E word-pairs of edge_index for zero hi-words.
__global__ void k_detect(const unsigned* __restrict__ x, long xwords,
                         const unsigned* __restrict__ ei, long epairs,
                         int* __restrict__ flag) {
    const long stride = 2048L * 256;
    if (blockIdx.x < 2048) {
        long i = (long)blockIdx.x * 256 + threadIdx.x;
        int c = 0;
        for (; i < xwords; i += stride) {
            unsigned w = x[i];
            if (((w >> 23) & 0xFFu) == 0xFFu || ((w >> 7) & 0xFFu) == 0xFFu) c++;
        }
        if (c) atomicAdd(&flag[0], c);
    } else {
        long i = (long)(blockIdx.x - 2048) * 256 + threadIdx.x;
        int c = 0;
        for (; i < epairs; i += stride)
            if (ei[2 * i + 1] == 0u) c++;
        if (c) atomicAdd(&flag[1], c);
    }
}

// ELL build, XCD-sliced: 8192 blocks = 2 passes x (8 xcd-groups x 512).
__global__ void k_build(const int* __restrict__ ei, int* __restrict__ indeg,
                        int* __restrict__ ebuf, int2* __restrict__ spill,
                        int* __restrict__ flag, int E, int N) {
    int blk = blockIdx.x;
    int pass = blk >> 12;
    int x = blk & 7;
    int q = (blk & 4095) >> 3;
    int s = pass * 8 + x;
    int sw = (N + SLICES - 1) / SLICES;
    int nlo = s * sw;
    int nhi = nlo + sw; if (nhi > N) nhi = N;
    bool is64 = flag[1] > (E >> 1);
    for (long e = (long)q * 256 + threadIdx.x; e < E; e += 512L * 256) {
        int d = is64 ? ei[2 * (E + e)] : ei[E + e];
        if (d < nlo || d >= nhi) continue;
        int src = is64 ? ei[2 * e] : ei[e];
        if ((unsigned)src >= (unsigned)N) continue;
        int c = atomicAdd(&indeg[d], 1);
        if (c < ELLS) {
            ebuf[(size_t)d * ELLS + c] = src;
        } else {
            int o = atomicAdd(&flag[2], 1);
            if (o < SPILL_CAP) spill[o] = make_int2(src, d);
        }
    }
}

__global__ void k_dinv(const int* __restrict__ indeg, float* __restrict__ dinv, int n) {
    int i = blockIdx.x * 256 + threadIdx.x;
    if (i < n) dinv[i] = rsqrtf(1.0f + (float)indeg[i]);  // deg includes self loop
}

// convert the 16 weight/bias arrays into the padded fp32 block (pads zeroed).
struct CW {
    const void* src[16];
    int off[16], rows[16], id[16], pd[16];
};
__global__ void k_convw(CW cw, float* __restrict__ dst, const int* __restrict__ flag) {
    int b = blockIdx.x;
    bool isf = flag[0] > 64;
    const float* sf = (const float*)cw.src[b];
    const unsigned short* sh = (const unsigned short*)cw.src[b];
    float* d = dst + cw.off[b];
    int id = cw.id[b], pd = cw.pd[b];
    int tot = cw.rows[b] * pd;
    for (int i = threadIdx.x; i < tot; i += 256) {
        int r = i / pd, c = i - r * pd;
        float v = 0.f;
        if (c < id) v = isf ? sf[r * id + c] : bf2f(sh[r * id + c]);
        d[i] = v;
    }
}

// g[i] = (x[i,100:150] @ Wg.T) * dinv[i] -> fp32 stride GS. Wg staged in LDS.
__global__ __launch_bounds__(256) void k_g(const void* __restrict__ xv,
                                           const float* __restrict__ W,
                                           const float* __restrict__ dinv,
                                           const int* __restrict__ flag,
                                           float* __restrict__ g, int n) {
    __shared__ float lwg[2600];  // 50 x 52
    {
        const float4* s4 = (const float4*)(W + O_WG);
        float4* d4 = (float4*)lwg;
        for (int k = threadIdx.x; k < 650; k += 256) d4[k] = s4[k];
    }
    __syncthreads();
    int i = blockIdx.x * 256 + threadIdx.x;
    if (i >= n) return;
    bool isf = flag[0] > 64;
    float xr[52];
    if (isf) {
        const float* p = (const float*)xv + (size_t)i * 150 + 100;
#pragma unroll
        for (int k = 0; k < 50; k++) xr[k] = p[k];
    } else {
        const unsigned short* p = (const unsigned short*)xv + (size_t)i * 150 + 100;
#pragma unroll
        for (int k = 0; k < 50; k++) xr[k] = bf2f(p[k]);
    }
    xr[50] = 0.f; xr[51] = 0.f;
    const float4* w4 = (const float4*)lwg;
    float di = dinv[i];
    float* gr = g + (size_t)i * GS;
#pragma unroll
    for (int f = 0; f < 50; f++) {
        float a = 0.f;
#pragma unroll
        for (int p = 0; p < 13; p++) {
            float4 w = w4[f * 13 + p];
            a += w.x * xr[4 * p] + w.y * xr[4 * p + 1] + w.z * xr[4 * p + 2] + w.w * xr[4 * p + 3];
        }
        gr[f] = a * di;
    }
}

// wave per node: lane f accumulates feature f over ELL edges; 8-way ILP.
__global__ __launch_bounds__(256) void k_gather(const float* __restrict__ g,
                                                const int* __restrict__ indeg,
                                                const int* __restrict__ ebuf,
                                                const float* __restrict__ dinv,
                                                const float* __restrict__ W,
                                                float* __restrict__ h1, int n) {
    int wid = threadIdx.x >> 6;
    int lane = threadIdx.x & 63;
    int i = blockIdx.x * 4 + wid;
    if (i >= n) return;
    int fc = lane < 50 ? lane : 49;
    int cnt = indeg[i];
    if (cnt > ELLS) cnt = ELLS;
    float di = dinv[i];
    int ev = (lane < cnt) ? ebuf[(size_t)i * ELLS + lane] : 0;
    float a0 = g[(size_t)i * GS + fc];  // self-loop (g pre-scaled by dinv[src])
    float a1 = 0.f, a2 = 0.f, a3 = 0.f, a4 = 0.f, a5 = 0.f, a6 = 0.f, a7 = 0.f;
    int m = 0;
    for (; m + 7 < cnt; m += 8) {
        int j0 = __shfl(ev, m);
        int j1 = __shfl(ev, m + 1);
        int j2 = __shfl(ev, m + 2);
        int j3 = __shfl(ev, m + 3);
        int j4 = __shfl(ev, m + 4);
        int j5 = __shfl(ev, m + 5);
        int j6 = __shfl(ev, m + 6);
        int j7 = __shfl(ev, m + 7);
        a0 += g[(size_t)j0 * GS + fc];
        a1 += g[(size_t)j1 * GS + fc];
        a2 += g[(size_t)j2 * GS + fc];
        a3 += g[(size_t)j3 * GS + fc];
        a4 += g[(size_t)j4 * GS + fc];
        a5 += g[(size_t)j5 * GS + fc];
        a6 += g[(size_t)j6 * GS + fc];
        a7 += g[(size_t)j7 * GS + fc];
    }
    for (; m < cnt; m++) {
        int j = __shfl(ev, m);
        a0 += g[(size_t)j * GS + fc];
    }
    if (lane < 50) {
        float h = (((a0 + a1) + (a2 + a3)) + ((a4 + a5) + (a6 + a7))) * di + W[O_BG + lane];
        h1[(size_t)i * 50 + lane] = h;
    }
}

// overflow edges (deg > ELLS): atomic-add their contribution into h1.
__global__ void k_spill(const int2* __restrict__ spill, const int* __restrict__ flag,
                        const float* __restrict__ g, const float* __restrict__ dinv,
                        float* __restrict__ h1) {
    int nov = flag[2];
    if (nov > SPILL_CAP) nov = SPILL_CAP;
    int lane = threadIdx.x & 63;
    int wave = (blockIdx.x * 256 + threadIdx.x) >> 6;
    for (int e = wave; e < nov; e += gridDim.x * 4) {
        int2 sd = spill[e];
        if (lane < 50)
            atomicAdd(&h1[(size_t)sd.y * 50 + lane], g[(size_t)sd.x * GS + lane] * dinv[sd.y]);
    }
}

// MLP chain: weights in LDS (float4 broadcast reads), ONE node per thread
// (R5 lesson: 2 nodes/thread + vgpr cap -> catastrophic scratch spill).
__global__ __launch_bounds__(256) void k_mlp(const float* __restrict__ h1,
                                             const void* __restrict__ epsv,
                                             const float* __restrict__ W,
                                             const int* __restrict__ flag,
                                             float* __restrict__ out, int n) {
    __shared__ float lw[MLP_LDS];
    {
        const float4* s4 = (const float4*)W;
        float4* d4 = (float4*)lw;
        for (int k = threadIdx.x; k < MLP_LDS / 4; k += 256) d4[k] = s4[k];
    }
    __syncthreads();
    const float4* lw4 = (const float4*)lw;
    int i = blockIdx.x * 256 + threadIdx.x;
    if (i >= n) return;
    bool isf = flag[0] > 64;

    float v0[52];
    {
        const float* hr = h1 + (size_t)i * 50;
#pragma unroll
        for (int p = 0; p < 50; p++) v0[p] = hr[p];
        v0[50] = 0.f; v0[51] = 0.f;
    }
    float v1[40];
#pragma unroll
    for (int f = 0; f < 40; f++) {
        float a = lw[O_BE1 + f];
#pragma unroll
        for (int p = 0; p < 13; p++) {
            float4 w = lw4[(O_WE1 >> 2) + f * 13 + p];
            a += w.x * v0[4 * p] + w.y * v0[4 * p + 1] + w.z * v0[4 * p + 2] + w.w * v0[4 * p + 3];
        }
        v1[f] = leaky(a);
    }
    float v2[32];
#pragma unroll
    for (int f = 0; f < 30; f++) {
        float a = lw[O_BE2 + f];
#pragma unroll
        for (int p = 0; p < 10; p++) {
            float4 w = lw4[(O_WE2 >> 2) + f * 10 + p];
            a += w.x * v1[4 * p] + w.y * v1[4 * p + 1] + w.z * v1[4 * p + 2] + w.w * v1[4 * p + 3];
        }
        v2[f] = leaky(a);
    }
    v2[30] = v2[31] = 0.f;

    float v3[20];  // [mu(10) | log_var(10)]
#pragma unroll
    for (int f = 0; f < 20; f++) {
        float a = lw[O_BE3 + f];
#pragma unroll
        for (int p = 0; p < 8; p++) {
            float4 w = lw4[(O_WE3 >> 2) + f * 8 + p];
            a += w.x * v2[4 * p] + w.y * v2[4 * p + 1] + w.z * v2[4 * p + 2] + w.w * v2[4 * p + 3];
        }
        v3[f] = a;
    }
    float z1[12];
    {
        float ev[10];
        if (isf) {
            const float* p = (const float*)epsv + (size_t)i * 10;
#pragma unroll
            for (int k = 0; k < 10; k++) ev[k] = p[k];
        } else {
            const unsigned short* p = (const unsigned short*)epsv + (size_t)i * 10;
#pragma unroll
            for (int k = 0; k < 10; k++) ev[k] = bf2f(p[k]);
        }
#pragma unroll
        for (int k = 0; k < 10; k++) z1[k] = v3[k] + ev[k] * expf(0.5f * v3[10 + k]);
        z1[10] = z1[11] = 0.f;
    }
    float z[12];
#pragma unroll
    for (int f = 0; f < 10; f++) {
        float a = lw[O_BFC + f];
#pragma unroll
        for (int p = 0; p < 3; p++) {
            float4 w = lw4[(O_WFC >> 2) + f * 3 + p];
            a += w.x * z1[4 * p] + w.y * z1[4 * p + 1] + w.z * z1[4 * p + 2] + w.w * z1[4 * p + 3];
        }
        z[f] = (a > 0.f) ? a : 0.f;
    }
    z[10] = z[11] = 0.f;

    float d1[20];
#pragma unroll
    for (int f = 0; f < 20; f++) {
        float a = lw[O_BD1 + f];
#pragma unroll
        for (int p = 0; p < 3; p++) {
            float4 w = lw4[(O_WD1 >> 2) + f * 3 + p];
            a += w.x * z[4 * p] + w.y * z[4 * p + 1] + w.z * z[4 * p + 2] + w.w * z[4 * p + 3];
        }
        d1[f] = leaky(a);
    }
    float d2[40];
#pragma unroll
    for (int f = 0; f < 40; f++) {
        float a = lw[O_BD2 + f];
#pragma unroll
        for (int p = 0; p < 5; p++) {
            float4 w = lw4[(O_WD2 >> 2) + f * 5 + p];
            a += w.x * d1[4 * p] + w.y * d1[4 * p + 1] + w.z * d1[4 * p + 2] + w.w * d1[4 * p + 3];
        }
        d2[f] = leaky(a);
    }
    // outputs (fp32): mu'(N*50) | mu(N*10) | log_var(N*10) | z(N*10)
    float* o_mup = out + (size_t)i * 50;
#pragma unroll
    for (int f = 0; f < 50; f++) {
        float a = lw[O_BD3 + f];
#pragma unroll
        for (int p = 0; p < 10; p++) {
            float4 w = lw4[(O_WD3 >> 2) + f * 10 + p];
            a += w.x * d2[4 * p] + w.y * d2[4 * p + 1] + w.z * d2[4 * p + 2] + w.w * d2[4 * p + 3];
        }
        o_mup[f] = 1.f / (1.f + expf(-a));
    }
    float* o_mu = out + (size_t)n * 50 + (size_t)i * 10;
    float* o_lv = out + (size_t)n * 60 + (size_t)i * 10;
    float* o_z = out + (size_t)n * 70 + (size_t)i * 10;
#pragma unroll
    for (int p = 0; p < 10; p++) {
        o_mu[p] = v3[p];
        o_lv[p] = v3[10 + p];
        o_z[p] = z[p];
    }
}

extern "C" void kernel_launch(void* const* d_in, const int* in_sizes, int n_in,
                              void* d_out, int out_size, void* d_ws, size_t ws_size,
                              hipStream_t stream) {
    const int N = in_sizes[0] / 150;
    const int E = in_sizes[1] / 2;

    char* w = (char*)d_ws;
    auto alloc = [&](size_t bytes) {
        void* p = (void*)w;
        w += (bytes + 255) & ~(size_t)255;
        return p;
    };
    int* indeg = (int*)alloc((size_t)N * 4);
    int* flag = (int*)alloc(256);
    float* dinv = (float*)alloc((size_t)N * 4);
    float* Wall = (float*)alloc((size_t)W_TOT * 4);
    int2* spill = (int2*)alloc((size_t)SPILL_CAP * 8);
    float* g = (float*)alloc((size_t)N * GS * 4);
    float* h1 = (float*)alloc((size_t)N * 50 * 4);
    int* ebuf = (int*)alloc((size_t)N * ELLS * 4);

    CW cw;
    static const int co[16] = {O_WG, O_BG, O_WE1, O_BE1, O_WE2, O_BE2, O_WE3, O_BE3,
                               O_WFC, O_BFC, O_WD1, O_BD1, O_WD2, O_BD2, O_WD3, O_BD3};
    static const int cr[16] = {50, 1, 40, 1, 30, 1, 20, 1, 10, 1, 20, 1, 40, 1, 50, 1};
    static const int ci[16] = {50, 50, 50, 40, 40, 30, 30, 20, 10, 10, 10, 20, 20, 40, 40, 50};
    static const int cp[16] = {52, 52, 52, 40, 40, 32, 32, 20, 12, 12, 12, 20, 20, 40, 40, 52};
    for (int k = 0; k < 16; k++) {
        cw.src[k] = d_in[3 + k];
        cw.off[k] = co[k];
        cw.rows[k] = cr[k];
        cw.id[k] = ci[k];
        cw.pd[k] = cp[k];
    }

    int nbN = (N + 255) / 256;

    k_zero<<<nbN, 256, 0, stream>>>(indeg, flag, N);
    k_detect<<<4096, 256, 0, stream>>>((const unsigned*)d_in[0], (long)N * 75,
                                       (const unsigned*)d_in[1], (long)E, flag);
    k_build<<<8192, 256, 0, stream>>>((const int*)d_in[1], indeg, ebuf, spill, flag, E, N);
    k_dinv<<<nbN, 256, 0, stream>>>(indeg, dinv, N);
    k_convw<<<16, 256, 0, stream>>>(cw, Wall, flag);
    k_g<<<nbN, 256, 0, stream>>>(d_in[0], Wall, dinv, flag, g, N);
    k_gather<<<(N + 3) / 4, 256, 0, stream>>>(g, indeg, ebuf, dinv, Wall, h1, N);
    k_spill<<<64, 256, 0, stream>>>(spill, flag, g, dinv, h1);
    k_mlp<<<nbN, 256, 0, stream>>>(h1, d_in[2], Wall, flag, (float*)d_out, N);
}